// Round 18
// baseline (351.284 us; speedup 1.0000x reference)
//
#include <hip/hip_runtime.h>
#include <hip/hip_bf16.h>

// ---------------- problem constants ----------------
#define D_MODEL 1024
#define N_HEADS 16
#define D_HEAD  64
#define D_FF    4096
#define SEQ     2048
#define BATCH   4
#define NROWS   (BATCH * SEQ)   // 8192

typedef __attribute__((ext_vector_type(8))) short short8;    // 8 x bf16 (4 VGPR)
typedef __attribute__((ext_vector_type(4))) float f32x4;     // 16x16 mfma acc

#define EXP2(x) exp2f(x)
#define MFMA16(a, b, c) __builtin_amdgcn_mfma_f32_16x16x32_bf16(a, b, c, 0, 0, 0)

static __device__ __forceinline__ ushort f2bf(float x) {
  __hip_bfloat16 h = __float2bfloat16(x);
  return *reinterpret_cast<ushort*>(&h);
}
static __device__ __forceinline__ float bf2f(ushort u) {
  unsigned int v = ((unsigned int)u) << 16;
  return *reinterpret_cast<float*>(&v);
}

// async global->LDS, 16B per lane. LDS dest is wave-uniform base (+lane*16 by HW).
static __device__ __forceinline__ void gl_lds16(const ushort* g, ushort* l) {
  __builtin_amdgcn_global_load_lds(
      (const __attribute__((address_space(1))) void*)g,
      (__attribute__((address_space(3))) void*)l, 16, 0, 0);
}

// ---------------- fused weight packing + LN1: 6 transpose jobs + 8192 LN rows -------
struct PackArgs {
  const float* in[6];
  ushort* out[6];
  int K[6], N[6], nx[6], per_batch[6];
  long in_bs[6], out_bs[6];
  int cum[7];
  const float* lnx; const float* lng; const float* lnb; ushort* lnout;
};

__global__ __launch_bounds__(256) void pack_ln(PackArgs a) {
  const int b = blockIdx.x;
  __shared__ float tile[32][33];

  if (b >= a.cum[6]) {
    // ---- LN1 row ----
    const int row = b - a.cum[6];
    const int t = threadIdx.y * 32 + threadIdx.x;
    const float4 v = *(const float4*)(a.lnx + (size_t)row * D_MODEL + t * 4);
    float s  = v.x + v.y + v.z + v.w;
    float ss = v.x * v.x + v.y * v.y + v.z * v.z + v.w * v.w;
#pragma unroll
    for (int off = 1; off < 64; off <<= 1) {
      s  += __shfl_xor(s, off, 64);
      ss += __shfl_xor(ss, off, 64);
    }
    float* red = &tile[0][0];
    const int w = t >> 6;
    if ((t & 63) == 0) { red[w] = s; red[4 + w] = ss; }
    __syncthreads();
    s  = red[0] + red[1] + red[2] + red[3];
    ss = red[4] + red[5] + red[6] + red[7];
    const float mu  = s * (1.0f / D_MODEL);
    const float var = ss * (1.0f / D_MODEL) - mu * mu;
    const float rstd = rsqrtf(var + 1e-5f);
    const float4 gg = *(const float4*)(a.lng + t * 4);
    const float4 bb = *(const float4*)(a.lnb + t * 4);
    ushort4 r;
    r.x = f2bf((v.x - mu) * rstd * gg.x + bb.x);
    r.y = f2bf((v.y - mu) * rstd * gg.y + bb.y);
    r.z = f2bf((v.z - mu) * rstd * gg.z + bb.z);
    r.w = f2bf((v.w - mu) * rstd * gg.w + bb.w);
    *(ushort4*)(a.lnout + (size_t)row * D_MODEL + t * 4) = r;
    return;
  }

  // ---- pack job ----
  int j = 0;
#pragma unroll
  for (int i = 0; i < 5; ++i) if (b >= a.cum[i + 1]) j = i + 1;
  const int tidx = b - a.cum[j];
  const int bz = tidx / a.per_batch[j];
  const int rem = tidx % a.per_batch[j];
  const int n0 = (rem % a.nx[j]) * 32;
  const int k0 = (rem / a.nx[j]) * 32;
  const float* in = a.in[j] + (long)bz * a.in_bs[j];
  ushort* out = a.out[j] + (long)bz * a.out_bs[j];
  const int K = a.K[j], N = a.N[j];

  const int tx = threadIdx.x, ty = threadIdx.y;
#pragma unroll
  for (int i = 0; i < 32; i += 8)
    tile[ty + i][tx] = in[(size_t)(k0 + ty + i) * N + n0 + tx];
  __syncthreads();
#pragma unroll
  for (int i = 0; i < 32; i += 8)
    out[(size_t)(n0 + ty + i) * K + k0 + tx] = f2bf(tile[tx][ty + i]);
}

// ---------------- LayerNorm (bf16 in, bf16 out) ----------------
__global__ __launch_bounds__(256) void ln_bf16_kernel(
    const ushort* __restrict__ x, const float* __restrict__ g,
    const float* __restrict__ b, ushort* __restrict__ out) {
  int row = blockIdx.x, t = threadIdx.x;
  const ushort4 u = *(const ushort4*)(x + (size_t)row * D_MODEL + t * 4);
  float4 v;
  v.x = bf2f(u.x); v.y = bf2f(u.y); v.z = bf2f(u.z); v.w = bf2f(u.w);
  float s  = v.x + v.y + v.z + v.w;
  float ss = v.x * v.x + v.y * v.y + v.z * v.z + v.w * v.w;
#pragma unroll
  for (int off = 1; off < 64; off <<= 1) {
    s  += __shfl_xor(s, off, 64);
    ss += __shfl_xor(ss, off, 64);
  }
  __shared__ float rs_[4], rss_[4];
  int w = t >> 6;
  if ((t & 63) == 0) { rs_[w] = s; rss_[w] = ss; }
  __syncthreads();
  s  = rs_[0] + rs_[1] + rs_[2] + rs_[3];
  ss = rss_[0] + rss_[1] + rss_[2] + rss_[3];
  float mu  = s * (1.0f / D_MODEL);
  float var = ss * (1.0f / D_MODEL) - mu * mu;
  float rstd = rsqrtf(var + 1e-5f);
  float4 gg = *(const float4*)(g + t * 4);
  float4 bb = *(const float4*)(b + t * 4);
  ushort4 r;
  r.x = f2bf((v.x - mu) * rstd * gg.x + bb.x);
  r.y = f2bf((v.y - mu) * rstd * gg.y + bb.y);
  r.z = f2bf((v.z - mu) * rstd * gg.z + bb.z);
  r.w = f2bf((v.w - mu) * rstd * gg.w + bb.w);
  *(ushort4*)(out + (size_t)row * D_MODEL + t * 4) = r;
}

// ---------------- 256x256 bf16 MFMA GEMM, counted-vmcnt double-buffer ---------------
// MODE 0: QKV (out0=q bf16 scaled, out1=k bf16, out2 = V TRANSPOSED [bh][d][s])
// MODE 2: FF1 relu -> bf16
template <int MODE>
__global__ __launch_bounds__(512, 2) void gemm256(
    const ushort* __restrict__ A, const ushort* __restrict__ BT,
    int M, int N, int K,
    const float* __restrict__ bias0, const float* __restrict__ bias1,
    const float* __restrict__ bias2,
    void* __restrict__ out0, void* __restrict__ out1, void* __restrict__ out2) {
  __shared__ __align__(16) ushort As[2][256 * 64];
  __shared__ __align__(16) ushort Bs[2][256 * 64];
  const int gx = N >> 8;
  const int nwg = gx * (M >> 8);
  const int cpx = nwg >> 3;
  const int tile = (blockIdx.x & 7) * cpx + (blockIdx.x >> 3);
  const int bn = tile % gx, bm = tile / gx;
  const int t = threadIdx.x, lane = t & 63, w = t >> 6;
  const int wr = w >> 2, wc = w & 3;
  const int l16 = lane & 15, l4 = lane >> 4;

  const ushort* Ab = A + (size_t)(bm * 256) * K;
  const ushort* Bb = BT + (size_t)(bn * 256) * K;

  int srow[4], scol[4];
#pragma unroll
  for (int i = 0; i < 4; ++i) {
    int c = i * 512 + t;
    srow[i] = c >> 3;
    scol[i] = 8 * ((c & 7) ^ ((c >> 3) & 7));
  }

  f32x4 acc[8][4] = {};
  int cur = 0;
  const int nk = K >> 6;

#pragma unroll
  for (int i = 0; i < 4; ++i) {
    gl_lds16(&Ab[(size_t)srow[i] * K + scol[i]], (ushort*)&As[0][(i * 512 + w * 64) * 8]);
    gl_lds16(&Bb[(size_t)srow[i] * K + scol[i]], (ushort*)&Bs[0][(i * 512 + w * 64) * 8]);
  }

  for (int kt = 0; kt < nk; ++kt) {
    if (kt + 1 < nk) {
      const int k0n = (kt + 1) << 6;
#pragma unroll
      for (int i = 0; i < 4; ++i) {
        gl_lds16(&Ab[(size_t)srow[i] * K + k0n + scol[i]], (ushort*)&As[cur ^ 1][(i * 512 + w * 64) * 8]);
        gl_lds16(&Bb[(size_t)srow[i] * K + k0n + scol[i]], (ushort*)&Bs[cur ^ 1][(i * 512 + w * 64) * 8]);
      }
      asm volatile("s_waitcnt vmcnt(8)" ::: "memory");  // prev tile landed; 8 in flight
    } else {
      asm volatile("s_waitcnt vmcnt(0)" ::: "memory");
    }
    __builtin_amdgcn_s_barrier();

    const ushort* As_ = As[cur];
    const ushort* Bs_ = Bs[cur];
    short8 bfr[4][2];
#pragma unroll
    for (int n = 0; n < 4; ++n) {
      const int row = wc * 64 + n * 16 + l16;
      const int sw = (row & 7) * 8;
      bfr[n][0] = *(const short8*)&Bs_[row * 64 + ((l4 * 8) ^ sw)];
      bfr[n][1] = *(const short8*)&Bs_[row * 64 + ((l4 * 8 + 32) ^ sw)];
    }
    __builtin_amdgcn_s_setprio(1);
#pragma unroll
    for (int m = 0; m < 8; ++m) {
      const int row = wr * 128 + m * 16 + l16;
      const int sw = (row & 7) * 8;
      short8 a0 = *(const short8*)&As_[row * 64 + ((l4 * 8) ^ sw)];
      short8 a1 = *(const short8*)&As_[row * 64 + ((l4 * 8 + 32) ^ sw)];
#pragma unroll
      for (int n = 0; n < 4; ++n) {
        acc[m][n] = MFMA16(a0, bfr[n][0], acc[m][n]);
        acc[m][n] = MFMA16(a1, bfr[n][1], acc[m][n]);
      }
    }
    __builtin_amdgcn_s_setprio(0);
    asm volatile("" ::: "memory");
    __builtin_amdgcn_s_barrier();   // ds_reads done before anyone overwrites cur
    cur ^= 1;
  }

  const int row0 = bm * 256 + wr * 128, col0 = bn * 256 + wc * 64;
#pragma unroll
  for (int m = 0; m < 8; ++m) {
#pragma unroll
    for (int n = 0; n < 4; ++n) {
      const int col = col0 + n * 16 + l16;
      if (MODE == 0) {
        const int which = col >> 10;          // uniform per fragment
        const int c = col & 1023;
        if (which < 2) {
          const float* bp_ = (which == 0) ? bias0 : bias1;
          ushort* op = (which == 0) ? (ushort*)out0 : (ushort*)out1;
          const float scale = (which == 0) ? 0.125f * 1.44269504f : 1.0f;
#pragma unroll
          for (int i = 0; i < 4; ++i) {
            const int row = row0 + m * 16 + l4 * 4 + i;
            op[(size_t)row * D_MODEL + c] = f2bf((acc[m][n][i] + bp_[c]) * scale);
          }
        } else {
          // v: write transposed into vt[bh][d][s]; 4 consecutive s per lane -> 8B store
          const int d = c & 63, hh2 = c >> 6;
          const float bv_ = bias2[c];
          ushort4 r4;
          r4.x = f2bf(acc[m][n][0] + bv_);
          r4.y = f2bf(acc[m][n][1] + bv_);
          r4.z = f2bf(acc[m][n][2] + bv_);
          r4.w = f2bf(acc[m][n][3] + bv_);
          const int row = row0 + m * 16 + l4 * 4;
          const int bb2 = row >> 11, s = row & 2047;
          *(ushort4*)((ushort*)out2 + ((size_t)(bb2 * 16 + hh2) * 64 + d) * SEQ + s) = r4;
        }
      } else {
#pragma unroll
        for (int i = 0; i < 4; ++i) {
          const int row = row0 + m * 16 + l4 * 4 + i;
          const float val = fmaxf(acc[m][n][i] + bias0[col], 0.0f);
          ((ushort*)out0)[(size_t)row * D_FF + col] = f2bf(val);
        }
      }
    }
  }
}

// ---------------- 128x128 dbuf counted-vmcnt GEMM (16x16 MFMA), 2 blocks/CU ---------
// RMODE 0 (proj): resid f32, out bf16 = C + bias + resid
// RMODE 1 (FF2):  resid bf16, out f32 = C + bias + resid
template <int RMODE>
__global__ __launch_bounds__(256, 2) void gemm128d(
    const ushort* __restrict__ A, const ushort* __restrict__ BT,
    int M, int N, int K,
    const float* __restrict__ bias0, const void* __restrict__ resid,
    void* __restrict__ out0) {
  __shared__ __align__(16) ushort As[2][128 * 64];
  __shared__ __align__(16) ushort Bs[2][128 * 64];
  const int gx = N >> 7;
  const int nwg = gx * (M >> 7);
  const int cpx = nwg >> 3;
  const int tile = (blockIdx.x & 7) * cpx + (blockIdx.x >> 3);
  const int bn = tile % gx, bm = tile / gx;
  const int t = threadIdx.x, lane = t & 63, w = t >> 6;
  const int wr = w >> 1, wc = w & 1;
  const int l16 = lane & 15, l4 = lane >> 4;

  const ushort* Ab = A + (size_t)(bm * 128) * K;
  const ushort* Bb = BT + (size_t)(bn * 128) * K;

  int srow[4], scol[4];
#pragma unroll
  for (int i = 0; i < 4; ++i) {
    int c = i * 256 + t;
    srow[i] = c >> 3;
    scol[i] = 8 * ((c & 7) ^ ((c >> 3) & 7));
  }

  f32x4 acc[4][4] = {};
  int cur = 0;
  const int nk = K >> 6;

#pragma unroll
  for (int i = 0; i < 4; ++i) {
    gl_lds16(&Ab[(size_t)srow[i] * K + scol[i]], (ushort*)&As[0][(i * 256 + w * 64) * 8]);
    gl_lds16(&Bb[(size_t)srow[i] * K + scol[i]], (ushort*)&Bs[0][(i * 256 + w * 64) * 8]);
  }

  for (int kt = 0; kt < nk; ++kt) {
    if (kt + 1 < nk) {
      const int k0n = (kt + 1) << 6;
#pragma unroll
      for (int i = 0; i < 4; ++i) {
        gl_lds16(&Ab[(size_t)srow[i] * K + k0n + scol[i]], (ushort*)&As[cur ^ 1][(i * 256 + w * 64) * 8]);
        gl_lds16(&Bb[(size_t)srow[i] * K + k0n + scol[i]], (ushort*)&Bs[cur ^ 1][(i * 256 + w * 64) * 8]);
      }
      asm volatile("s_waitcnt vmcnt(8)" ::: "memory");
    } else {
      asm volatile("s_waitcnt vmcnt(0)" ::: "memory");
    }
    __builtin_amdgcn_s_barrier();

    const ushort* As_ = As[cur];
    const ushort* Bs_ = Bs[cur];
    short8 bfr[4][2];
#pragma unroll
    for (int n = 0; n < 4; ++n) {
      const int row = wc * 64 + n * 16 + l16;
      const int sw = (row & 7) * 8;
      bfr[n][0] = *(const short8*)&Bs_[row * 64 + ((l4 * 8) ^ sw)];
      bfr[n][1] = *(const short8*)&Bs_[row * 64 + ((l4 * 8 + 32) ^ sw)];
    }
    __builtin_amdgcn_s_setprio(1);
#pragma unroll
    for (int m = 0; m < 4; ++m) {
      const int row = wr * 64 + m * 16 + l16;
      const int sw = (row & 7) * 8;
      short8 a0 = *(const short8*)&As_[row * 64 + ((l4 * 8) ^ sw)];
      short8 a1 = *(const short8*)&As_[row * 64 + ((l4 * 8 + 32) ^ sw)];
#pragma unroll
      for (int n = 0; n < 4; ++n) {
        acc[m][n] = MFMA16(a0, bfr[n][0], acc[m][n]);
        acc[m][n] = MFMA16(a1, bfr[n][1], acc[m][n]);
      }
    }
    __builtin_amdgcn_s_setprio(0);
    asm volatile("" ::: "memory");
    __builtin_amdgcn_s_barrier();
    cur ^= 1;
  }

  const int row0 = bm * 128 + wr * 64, col0 = bn * 128 + wc * 64;
#pragma unroll
  for (int m = 0; m < 4; ++m) {
#pragma unroll
    for (int n = 0; n < 4; ++n) {
      const int col = col0 + n * 16 + l16;
#pragma unroll
      for (int i = 0; i < 4; ++i) {
        const int row = row0 + m * 16 + l4 * 4 + i;
        const size_t idx = (size_t)row * D_MODEL + col;
        if (RMODE == 0) {
          const float rv = ((const float*)resid)[idx];
          ((ushort*)out0)[idx] = f2bf(acc[m][n][i] + bias0[col] + rv);
        } else {
          const float rv = bf2f(((const ushort*)resid)[idx]);
          ((float*)out0)[idx] = acc[m][n][i] + bias0[col] + rv;
        }
      }
    }
  }
}

// ---------------- causal flash attention v8: paired KV tiles, 4-deep ring ------------
__global__ __launch_bounds__(256) void attn8_kernel(
    const ushort* __restrict__ Q, const ushort* __restrict__ Km,
    const ushort* __restrict__ Vt, ushort* __restrict__ O) {
  const int b = blockIdx.x;
  const int bh = (b & 7) * 8 + ((b >> 3) & 7);
  const int p = b >> 6;                      // 0..7
  const int bb = bh >> 4, hh = bh & 15;
  const int t = threadIdx.x, lane = t & 63, w = t >> 6;
  const int l16 = lane & 15, l4 = lane >> 4;
  const size_t base  = (size_t)bb * SEQ * D_MODEL + (size_t)hh * 64;
  const size_t vbase = (size_t)bh * 64 * SEQ;

  __shared__ __align__(16) ushort Ks[4][64 * 64];
  __shared__ __align__(16) ushort Vs[4][64 * 64];
  __shared__ __align__(16) ushort Pw[4][32 * 64];
  ushort* myP = &Pw[w][0];

#define STAGE(ktile, buf) do {                                                     \
    const int kv0_ = (ktile) * 64;                                                 \
    _Pragma("unroll")                                                              \
    for (int i_ = 0; i_ < 2; ++i_) {                                               \
      const int g_ = i_ * 256 + t;                                                 \
      const int row_ = g_ >> 3;                                                    \
      const int c8_ = ((g_ & 7) ^ (row_ & 7)) * 8;                                 \
      gl_lds16(&Km[base + (size_t)(kv0_ + row_) * D_MODEL + c8_],                  \
               (ushort*)&Ks[buf][(i_ * 256 + w * 64) * 8]);                        \
      gl_lds16(&Vt[vbase + (size_t)row_ * SEQ + kv0_ + c8_],                       \
               (ushort*)&Vs[buf][(i_ * 256 + w * 64) * 8]);                        \
    }                                                                              \
  } while (0)

#pragma unroll
  for (int pan = 0; pan < 2; ++pan) {
    const int qt = pan ? p : (15 - p);
    const int qb = qt * 128 + w * 32;
    const int nt = qt * 2 + 2;

    short8 qf[2][2];
#pragma unroll
    for (int qj = 0; qj < 2; ++qj)
#pragma unroll
      for (int dk = 0; dk < 2; ++dk)
        qf[qj][dk] = *(const short8*)&Q[base + (size_t)(qb + qj * 16 + l16) * D_MODEL + dk * 32 + l4 * 8];

    f32x4 oacc[4][2] = {};
    float l_i[2] = {0.0f, 0.0f};

    STAGE(0, 0);
    STAGE(1, 1);

    for (int jt = 0; jt < nt; jt += 2) {
      if (jt + 2 < nt) {
        STAGE(jt + 2, (jt + 2) & 3);
        STAGE(jt + 3, (jt + 3) & 3);
        asm volatile("s_waitcnt vmcnt(8)" ::: "memory");
      } else {
        asm volatile("s_waitcnt vmcnt(0)" ::: "memory");
      }
      __builtin_amdgcn_s_barrier();

#pragma unroll
      for (int half = 0; half < 2; ++half) {
        const int kt = jt + half;
        const int kv0 = kt * 64;
        const bool active = (kv0 <= qb + 31);
        if (active) {
          const ushort* Kc = Ks[kt & 3];
          const ushort* Vc = Vs[kt & 3];

          f32x4 sacc[2][4] = {};
          __builtin_amdgcn_s_setprio(1);
#pragma unroll
          for (int n = 0; n < 4; ++n) {
            const int r = n * 16 + l16;
            const int rs = r * 8, rx = r & 7;
#pragma unroll
            for (int dk = 0; dk < 2; ++dk) {
              short8 ak = *(const short8*)&Kc[(rs + ((dk * 4 + l4) ^ rx)) * 8];
              sacc[0][n] = MFMA16(ak, qf[0][dk], sacc[0][n]);
              sacc[1][n] = MFMA16(ak, qf[1][dk], sacc[1][n]);
            }
          }
          __builtin_amdgcn_s_setprio(0);

          const bool diag = (kv0 + 63 > qb);
#pragma unroll
          for (int qj = 0; qj < 2; ++qj) {
            const int qq = qb + qj * 16 + l16;
            const int ql = qj * 16 + l16;
            const int psw = (ql & 7) * 8;
            if (diag) {
#pragma unroll
              for (int n = 0; n < 4; ++n)
#pragma unroll
                for (int i = 0; i < 4; ++i) {
                  const int kv = kv0 + n * 16 + l4 * 4 + i;
                  if (kv > qq) sacc[qj][n][i] = -1e30f;
                }
            }
            float lsum = 0.0f;
#pragma unroll
            for (int n = 0; n < 4; ++n) {
              const float p0 = EXP2(sacc[qj][n][0]);
              const float p1 = EXP2(sacc[qj][n][1]);
              const float p2 = EXP2(sacc[qj][n][2]);
              const float p3 = EXP2(sacc[qj][n][3]);
              lsum += p0 + p1 + p2 + p3;
              ushort4 pk;
              pk.x = f2bf(p0); pk.y = f2bf(p1); pk.z = f2bf(p2); pk.w = f2bf(p3);
              *(ushort4*)&myP[ql * 64 + ((n * 16 + l4 * 4) ^ psw)] = pk;
            }
            l_i[qj] += lsum;
          }

          __builtin_amdgcn_s_setprio(1);
#pragma unroll
          for (int kk = 0; kk < 2; ++kk) {
            short8 bp[2];
#pragma unroll
            for (int qj = 0; qj < 2; ++qj) {
              const int ql = qj * 16 + l16;
              bp[qj] = *(const short8*)&myP[ql * 64 + ((kk * 32 + l4 * 8) ^ ((ql & 7) * 8))];
            }
#pragma unroll
            for (int nd = 0; nd < 4; ++nd) {
              const int r = nd * 16 + l16;
              short8 av = *(const short8*)&Vc[(r * 8 + ((kk * 4 + l4) ^ (r & 7))) * 8];
              oacc[nd][0] = MFMA16(av, bp[0], oacc[nd][0]);
              oacc[nd][1] = MFMA16(av, bp[1], oacc[nd][1]);
            }
          }
          __builtin_amdgcn_s_setprio(0);
        }
      }

      asm volatile("" ::: "memory");
      __builtin_amdgcn_s_barrier();
    }

#pragma unroll
    for (int qj = 0; qj < 2; ++qj) {
      l_i[qj] += __shfl_xor(l_i[qj], 16, 64);
      l_i[qj] += __shfl_xor(l_i[qj], 32, 64);
      const int qq = qb + qj * 16 + l16;
      const float inv = 1.0f / l_i[qj];
#pragma unroll
      for (int nd = 0; nd < 4; ++nd) {
        ushort4 r;
        r.x = f2bf(oacc[nd][qj][0] * inv);
        r.y = f2bf(oacc[nd][qj][1] * inv);
        r.z = f2bf(oacc[nd][qj][2] * inv);
        r.w = f2bf(oacc[nd][qj][3] * inv);
        *(ushort4*)&O[base + (size_t)qq * D_MODEL + nd * 16 + l4 * 4] = r;
      }
    }
  }
#undef STAGE
}

// ---------------- host launch ----------------
extern "C" void kernel_launch(void* const* d_in, const int* in_sizes, int n_in,
                              void* d_out, int out_size, void* d_ws, size_t ws_size,
                              hipStream_t stream) {
  const float* x    = (const float*)d_in[0];
  const float* ln1g = (const float*)d_in[1];
  const float* ln1b = (const float*)d_in[2];
  const float* wq   = (const float*)d_in[3];
  const float* bq   = (const float*)d_in[4];
  const float* wk   = (const float*)d_in[5];
  const float* bk   = (const float*)d_in[6];
  const float* wv   = (const float*)d_in[7];
  const float* bv   = (const float*)d_in[8];
  const float* wp   = (const float*)d_in[9];
  const float* bp   = (const float*)d_in[10];
  const float* ln2g = (const float*)d_in[11];
  const float* ln2b = (const float*)d_in[12];
  const float* w1   = (const float*)d_in[13];
  const float* b1   = (const float*)d_in[14];
  const float* w2   = (const float*)d_in[15];
  const float* b2   = (const float*)d_in[16];
  float* out = (float*)d_out;

  char* base = (char*)d_ws;
  size_t off = 0;
  auto alloc = [&](size_t bytes) -> void* {
    void* r = base + off;
    off += (bytes + 255) & ~(size_t)255;
    return r;
  };
  ushort* WqkvT = (ushort*)alloc((size_t)3 * D_MODEL * D_MODEL * 2);
  ushort* WpT   = (ushort*)alloc((size_t)D_MODEL * D_MODEL * 2);
  ushort* W1T   = (ushort*)alloc((size_t)D_FF * D_MODEL * 2);
  ushort* W2T   = (ushort*)alloc((size_t)D_MODEL * D_FF * 2);
  ushort* xn    = (ushort*)alloc((size_t)NROWS * D_MODEL * 2);
  ushort* q     = (ushort*)alloc((size_t)NROWS * D_MODEL * 2);
  ushort* k     = (ushort*)alloc((size_t)NROWS * D_MODEL * 2);
  ushort* vt    = (ushort*)alloc((size_t)NROWS * D_MODEL * 2);  // [bh][d][s]
  ushort* o     = (ushort*)alloc((size_t)NROWS * D_MODEL * 2);
  ushort* x2    = (ushort*)alloc((size_t)NROWS * D_MODEL * 2);  // bf16 residual stream
  ushort* xn2   = (ushort*)alloc((size_t)NROWS * D_MODEL * 2);
  ushort* hbuf  = (ushort*)alloc((size_t)NROWS * D_FF * 2);

  // fused weight packing + LN1: 12288 pack blocks + 8192 LN rows
  PackArgs pa;
  pa.in[0] = wq; pa.out[0] = WqkvT + (size_t)0 * D_MODEL * D_MODEL;
  pa.in[1] = wk; pa.out[1] = WqkvT + (size_t)1 * D_MODEL * D_MODEL;
  pa.in[2] = wv; pa.out[2] = WqkvT + (size_t)2 * D_MODEL * D_MODEL;
  pa.in[3] = wp; pa.out[3] = WpT;
  pa.in[4] = w1; pa.out[4] = W1T;
  pa.in[5] = w2; pa.out[5] = W2T;
  for (int j = 0; j < 3; ++j) {
    pa.K[j] = D_MODEL; pa.N[j] = D_HEAD; pa.nx[j] = 2; pa.per_batch[j] = 64;
    pa.in_bs[j] = (long)D_MODEL * D_HEAD; pa.out_bs[j] = (long)D_HEAD * D_MODEL;
  }
  pa.K[3] = D_MODEL; pa.N[3] = D_MODEL; pa.nx[3] = 32; pa.per_batch[3] = 1024;
  pa.in_bs[3] = 0; pa.out_bs[3] = 0;
  pa.K[4] = D_MODEL; pa.N[4] = D_FF; pa.nx[4] = 128; pa.per_batch[4] = 4096;
  pa.in_bs[4] = 0; pa.out_bs[4] = 0;
  pa.K[5] = D_FF; pa.N[5] = D_MODEL; pa.nx[5] = 32; pa.per_batch[5] = 4096;
  pa.in_bs[5] = 0; pa.out_bs[5] = 0;
  pa.cum[0] = 0; pa.cum[1] = 1024; pa.cum[2] = 2048; pa.cum[3] = 3072;
  pa.cum[4] = 4096; pa.cum[5] = 8192; pa.cum[6] = 12288;
  pa.lnx = x; pa.lng = ln1g; pa.lnb = ln1b; pa.lnout = xn;
  pack_ln<<<12288 + NROWS, dim3(32, 8), 0, stream>>>(pa);

  gemm256<0><<<dim3((NROWS / 256) * (3 * D_MODEL / 256)), 512, 0, stream>>>(
      xn, WqkvT, NROWS, 3 * D_MODEL, D_MODEL, bq, bk, bv, q, k, vt);
  attn8_kernel<<<512, 256, 0, stream>>>(q, k, vt, o);
  // proj: resid = x (f32), out = x2 (bf16)
  gemm128d<0><<<dim3((NROWS / 128) * (D_MODEL / 128)), 256, 0, stream>>>(
      o, WpT, NROWS, D_MODEL, D_MODEL, bp, x, x2);
  ln_bf16_kernel<<<NROWS, 256, 0, stream>>>(x2, ln2g, ln2b, xn2);
  gemm256<2><<<dim3((NROWS / 256) * (D_FF / 256)), 512, 0, stream>>>(
      xn2, W1T, NROWS, D_FF, D_MODEL, b1, nullptr, nullptr, hbuf, nullptr, nullptr);
  // FF2: resid = x2 (bf16), out = d_out (f32)
  gemm128d<1><<<dim3((NROWS / 128) * (D_MODEL / 128)), 256, 0, stream>>>(
      hbuf, W2T, NROWS, D_MODEL, D_FF, b2, x2, out);
}

// Round 19
// 345.653 us; speedup vs baseline: 1.0163x; 1.0163x over previous
//
#include <hip/hip_runtime.h>
#include <hip/hip_bf16.h>

// ---------------- problem constants ----------------
#define D_MODEL 1024
#define N_HEADS 16
#define D_HEAD  64
#define D_FF    4096
#define SEQ     2048
#define BATCH   4
#define NROWS   (BATCH * SEQ)   // 8192

typedef __attribute__((ext_vector_type(8))) short short8;    // 8 x bf16 (4 VGPR)
typedef __attribute__((ext_vector_type(4))) float f32x4;     // 16x16 mfma acc

#define EXP2(x) exp2f(x)
#define MFMA16(a, b, c) __builtin_amdgcn_mfma_f32_16x16x32_bf16(a, b, c, 0, 0, 0)

static __device__ __forceinline__ ushort f2bf(float x) {
  __hip_bfloat16 h = __float2bfloat16(x);
  return *reinterpret_cast<ushort*>(&h);
}
static __device__ __forceinline__ float bf2f(ushort u) {
  unsigned int v = ((unsigned int)u) << 16;
  return *reinterpret_cast<float*>(&v);
}

// async global->LDS, 16B per lane. LDS dest is wave-uniform base (+lane*16 by HW).
static __device__ __forceinline__ void gl_lds16(const ushort* g, ushort* l) {
  __builtin_amdgcn_global_load_lds(
      (const __attribute__((address_space(1))) void*)g,
      (__attribute__((address_space(3))) void*)l, 16, 0, 0);
}

// ---------------- fused weight packing + LN1: 6 transpose jobs + 8192 LN rows -------
struct PackArgs {
  const float* in[6];
  ushort* out[6];
  int K[6], N[6], nx[6], per_batch[6];
  long in_bs[6], out_bs[6];
  int cum[7];
  const float* lnx; const float* lng; const float* lnb; ushort* lnout;
};

__global__ __launch_bounds__(256) void pack_ln(PackArgs a) {
  const int b = blockIdx.x;
  __shared__ float tile[32][33];

  if (b >= a.cum[6]) {
    // ---- LN1 row ----
    const int row = b - a.cum[6];
    const int t = threadIdx.y * 32 + threadIdx.x;
    const float4 v = *(const float4*)(a.lnx + (size_t)row * D_MODEL + t * 4);
    float s  = v.x + v.y + v.z + v.w;
    float ss = v.x * v.x + v.y * v.y + v.z * v.z + v.w * v.w;
#pragma unroll
    for (int off = 1; off < 64; off <<= 1) {
      s  += __shfl_xor(s, off, 64);
      ss += __shfl_xor(ss, off, 64);
    }
    float* red = &tile[0][0];
    const int w = t >> 6;
    if ((t & 63) == 0) { red[w] = s; red[4 + w] = ss; }
    __syncthreads();
    s  = red[0] + red[1] + red[2] + red[3];
    ss = red[4] + red[5] + red[6] + red[7];
    const float mu  = s * (1.0f / D_MODEL);
    const float var = ss * (1.0f / D_MODEL) - mu * mu;
    const float rstd = rsqrtf(var + 1e-5f);
    const float4 gg = *(const float4*)(a.lng + t * 4);
    const float4 bb = *(const float4*)(a.lnb + t * 4);
    ushort4 r;
    r.x = f2bf((v.x - mu) * rstd * gg.x + bb.x);
    r.y = f2bf((v.y - mu) * rstd * gg.y + bb.y);
    r.z = f2bf((v.z - mu) * rstd * gg.z + bb.z);
    r.w = f2bf((v.w - mu) * rstd * gg.w + bb.w);
    *(ushort4*)(a.lnout + (size_t)row * D_MODEL + t * 4) = r;
    return;
  }

  // ---- pack job ----
  int j = 0;
#pragma unroll
  for (int i = 0; i < 5; ++i) if (b >= a.cum[i + 1]) j = i + 1;
  const int tidx = b - a.cum[j];
  const int bz = tidx / a.per_batch[j];
  const int rem = tidx % a.per_batch[j];
  const int n0 = (rem % a.nx[j]) * 32;
  const int k0 = (rem / a.nx[j]) * 32;
  const float* in = a.in[j] + (long)bz * a.in_bs[j];
  ushort* out = a.out[j] + (long)bz * a.out_bs[j];
  const int K = a.K[j], N = a.N[j];

  const int tx = threadIdx.x, ty = threadIdx.y;
#pragma unroll
  for (int i = 0; i < 32; i += 8)
    tile[ty + i][tx] = in[(size_t)(k0 + ty + i) * N + n0 + tx];
  __syncthreads();
#pragma unroll
  for (int i = 0; i < 32; i += 8)
    out[(size_t)(n0 + ty + i) * K + k0 + tx] = f2bf(tile[tx][ty + i]);
}

// ---------------- LayerNorm (bf16 in, bf16 out) ----------------
__global__ __launch_bounds__(256) void ln_bf16_kernel(
    const ushort* __restrict__ x, const float* __restrict__ g,
    const float* __restrict__ b, ushort* __restrict__ out) {
  int row = blockIdx.x, t = threadIdx.x;
  const ushort4 u = *(const ushort4*)(x + (size_t)row * D_MODEL + t * 4);
  float4 v;
  v.x = bf2f(u.x); v.y = bf2f(u.y); v.z = bf2f(u.z); v.w = bf2f(u.w);
  float s  = v.x + v.y + v.z + v.w;
  float ss = v.x * v.x + v.y * v.y + v.z * v.z + v.w * v.w;
#pragma unroll
  for (int off = 1; off < 64; off <<= 1) {
    s  += __shfl_xor(s, off, 64);
    ss += __shfl_xor(ss, off, 64);
  }
  __shared__ float rs_[4], rss_[4];
  int w = t >> 6;
  if ((t & 63) == 0) { rs_[w] = s; rss_[w] = ss; }
  __syncthreads();
  s  = rs_[0] + rs_[1] + rs_[2] + rs_[3];
  ss = rss_[0] + rss_[1] + rss_[2] + rss_[3];
  float mu  = s * (1.0f / D_MODEL);
  float var = ss * (1.0f / D_MODEL) - mu * mu;
  float rstd = rsqrtf(var + 1e-5f);
  float4 gg = *(const float4*)(g + t * 4);
  float4 bb = *(const float4*)(b + t * 4);
  ushort4 r;
  r.x = f2bf((v.x - mu) * rstd * gg.x + bb.x);
  r.y = f2bf((v.y - mu) * rstd * gg.y + bb.y);
  r.z = f2bf((v.z - mu) * rstd * gg.z + bb.z);
  r.w = f2bf((v.w - mu) * rstd * gg.w + bb.w);
  *(ushort4*)(out + (size_t)row * D_MODEL + t * 4) = r;
}

// ---------------- 256x256 bf16 MFMA GEMM, counted-vmcnt double-buffer ---------------
// MODE 0: QKV (out0=q bf16 scaled, out1=k bf16, out2 = V TRANSPOSED [bh][d][s])
// MODE 2: FF1 relu -> bf16   (NO setprio: 8-wave lockstep = m190 null/neg regime)
template <int MODE>
__global__ __launch_bounds__(512, 2) void gemm256(
    const ushort* __restrict__ A, const ushort* __restrict__ BT,
    int M, int N, int K,
    const float* __restrict__ bias0, const float* __restrict__ bias1,
    const float* __restrict__ bias2,
    void* __restrict__ out0, void* __restrict__ out1, void* __restrict__ out2) {
  __shared__ __align__(16) ushort As[2][256 * 64];
  __shared__ __align__(16) ushort Bs[2][256 * 64];
  const int gx = N >> 8;
  const int nwg = gx * (M >> 8);
  const int cpx = nwg >> 3;
  const int tile = (blockIdx.x & 7) * cpx + (blockIdx.x >> 3);
  const int bn = tile % gx, bm = tile / gx;
  const int t = threadIdx.x, lane = t & 63, w = t >> 6;
  const int wr = w >> 2, wc = w & 3;
  const int l16 = lane & 15, l4 = lane >> 4;

  const ushort* Ab = A + (size_t)(bm * 256) * K;
  const ushort* Bb = BT + (size_t)(bn * 256) * K;

  int srow[4], scol[4];
#pragma unroll
  for (int i = 0; i < 4; ++i) {
    int c = i * 512 + t;
    srow[i] = c >> 3;
    scol[i] = 8 * ((c & 7) ^ ((c >> 3) & 7));
  }

  f32x4 acc[8][4] = {};
  int cur = 0;
  const int nk = K >> 6;

#pragma unroll
  for (int i = 0; i < 4; ++i) {
    gl_lds16(&Ab[(size_t)srow[i] * K + scol[i]], (ushort*)&As[0][(i * 512 + w * 64) * 8]);
    gl_lds16(&Bb[(size_t)srow[i] * K + scol[i]], (ushort*)&Bs[0][(i * 512 + w * 64) * 8]);
  }

  for (int kt = 0; kt < nk; ++kt) {
    if (kt + 1 < nk) {
      const int k0n = (kt + 1) << 6;
#pragma unroll
      for (int i = 0; i < 4; ++i) {
        gl_lds16(&Ab[(size_t)srow[i] * K + k0n + scol[i]], (ushort*)&As[cur ^ 1][(i * 512 + w * 64) * 8]);
        gl_lds16(&Bb[(size_t)srow[i] * K + k0n + scol[i]], (ushort*)&Bs[cur ^ 1][(i * 512 + w * 64) * 8]);
      }
      asm volatile("s_waitcnt vmcnt(8)" ::: "memory");  // prev tile landed; 8 in flight
    } else {
      asm volatile("s_waitcnt vmcnt(0)" ::: "memory");
    }
    __builtin_amdgcn_s_barrier();

    const ushort* As_ = As[cur];
    const ushort* Bs_ = Bs[cur];
    short8 bfr[4][2];
#pragma unroll
    for (int n = 0; n < 4; ++n) {
      const int row = wc * 64 + n * 16 + l16;
      const int sw = (row & 7) * 8;
      bfr[n][0] = *(const short8*)&Bs_[row * 64 + ((l4 * 8) ^ sw)];
      bfr[n][1] = *(const short8*)&Bs_[row * 64 + ((l4 * 8 + 32) ^ sw)];
    }
#pragma unroll
    for (int m = 0; m < 8; ++m) {
      const int row = wr * 128 + m * 16 + l16;
      const int sw = (row & 7) * 8;
      short8 a0 = *(const short8*)&As_[row * 64 + ((l4 * 8) ^ sw)];
      short8 a1 = *(const short8*)&As_[row * 64 + ((l4 * 8 + 32) ^ sw)];
#pragma unroll
      for (int n = 0; n < 4; ++n) {
        acc[m][n] = MFMA16(a0, bfr[n][0], acc[m][n]);
        acc[m][n] = MFMA16(a1, bfr[n][1], acc[m][n]);
      }
    }
    asm volatile("" ::: "memory");
    __builtin_amdgcn_s_barrier();   // ds_reads done before anyone overwrites cur
    cur ^= 1;
  }

  const int row0 = bm * 256 + wr * 128, col0 = bn * 256 + wc * 64;
#pragma unroll
  for (int m = 0; m < 8; ++m) {
#pragma unroll
    for (int n = 0; n < 4; ++n) {
      const int col = col0 + n * 16 + l16;
      if (MODE == 0) {
        const int which = col >> 10;          // uniform per fragment
        const int c = col & 1023;
        if (which < 2) {
          const float* bp_ = (which == 0) ? bias0 : bias1;
          ushort* op = (which == 0) ? (ushort*)out0 : (ushort*)out1;
          const float scale = (which == 0) ? 0.125f * 1.44269504f : 1.0f;
#pragma unroll
          for (int i = 0; i < 4; ++i) {
            const int row = row0 + m * 16 + l4 * 4 + i;
            op[(size_t)row * D_MODEL + c] = f2bf((acc[m][n][i] + bp_[c]) * scale);
          }
        } else {
          // v: write transposed into vt[bh][d][s]; 4 consecutive s per lane -> 8B store
          const int d = c & 63, hh2 = c >> 6;
          const float bv_ = bias2[c];
          ushort4 r4;
          r4.x = f2bf(acc[m][n][0] + bv_);
          r4.y = f2bf(acc[m][n][1] + bv_);
          r4.z = f2bf(acc[m][n][2] + bv_);
          r4.w = f2bf(acc[m][n][3] + bv_);
          const int row = row0 + m * 16 + l4 * 4;
          const int bb2 = row >> 11, s = row & 2047;
          *(ushort4*)((ushort*)out2 + ((size_t)(bb2 * 16 + hh2) * 64 + d) * SEQ + s) = r4;
        }
      } else {
#pragma unroll
        for (int i = 0; i < 4; ++i) {
          const int row = row0 + m * 16 + l4 * 4 + i;
          const float val = fmaxf(acc[m][n][i] + bias0[col], 0.0f);
          ((ushort*)out0)[(size_t)row * D_FF + col] = f2bf(val);
        }
      }
    }
  }
}

// ---------------- 128x128 dbuf counted-vmcnt GEMM (16x16 MFMA), 2 blocks/CU ---------
// RMODE 0 (proj): resid f32, out bf16 = C + bias + resid
// RMODE 1 (FF2):  resid bf16, out f32 = C + bias + resid
template <int RMODE>
__global__ __launch_bounds__(256, 2) void gemm128d(
    const ushort* __restrict__ A, const ushort* __restrict__ BT,
    int M, int N, int K,
    const float* __restrict__ bias0, const void* __restrict__ resid,
    void* __restrict__ out0) {
  __shared__ __align__(16) ushort As[2][128 * 64];
  __shared__ __align__(16) ushort Bs[2][128 * 64];
  const int gx = N >> 7;
  const int nwg = gx * (M >> 7);
  const int cpx = nwg >> 3;
  const int tile = (blockIdx.x & 7) * cpx + (blockIdx.x >> 3);
  const int bn = tile % gx, bm = tile / gx;
  const int t = threadIdx.x, lane = t & 63, w = t >> 6;
  const int wr = w >> 1, wc = w & 1;
  const int l16 = lane & 15, l4 = lane >> 4;

  const ushort* Ab = A + (size_t)(bm * 128) * K;
  const ushort* Bb = BT + (size_t)(bn * 128) * K;

  int srow[4], scol[4];
#pragma unroll
  for (int i = 0; i < 4; ++i) {
    int c = i * 256 + t;
    srow[i] = c >> 3;
    scol[i] = 8 * ((c & 7) ^ ((c >> 3) & 7));
  }

  f32x4 acc[4][4] = {};
  int cur = 0;
  const int nk = K >> 6;

#pragma unroll
  for (int i = 0; i < 4; ++i) {
    gl_lds16(&Ab[(size_t)srow[i] * K + scol[i]], (ushort*)&As[0][(i * 256 + w * 64) * 8]);
    gl_lds16(&Bb[(size_t)srow[i] * K + scol[i]], (ushort*)&Bs[0][(i * 256 + w * 64) * 8]);
  }

  for (int kt = 0; kt < nk; ++kt) {
    if (kt + 1 < nk) {
      const int k0n = (kt + 1) << 6;
#pragma unroll
      for (int i = 0; i < 4; ++i) {
        gl_lds16(&Ab[(size_t)srow[i] * K + k0n + scol[i]], (ushort*)&As[cur ^ 1][(i * 256 + w * 64) * 8]);
        gl_lds16(&Bb[(size_t)srow[i] * K + k0n + scol[i]], (ushort*)&Bs[cur ^ 1][(i * 256 + w * 64) * 8]);
      }
      asm volatile("s_waitcnt vmcnt(8)" ::: "memory");
    } else {
      asm volatile("s_waitcnt vmcnt(0)" ::: "memory");
    }
    __builtin_amdgcn_s_barrier();

    const ushort* As_ = As[cur];
    const ushort* Bs_ = Bs[cur];
    short8 bfr[4][2];
#pragma unroll
    for (int n = 0; n < 4; ++n) {
      const int row = wc * 64 + n * 16 + l16;
      const int sw = (row & 7) * 8;
      bfr[n][0] = *(const short8*)&Bs_[row * 64 + ((l4 * 8) ^ sw)];
      bfr[n][1] = *(const short8*)&Bs_[row * 64 + ((l4 * 8 + 32) ^ sw)];
    }
    __builtin_amdgcn_s_setprio(1);
#pragma unroll
    for (int m = 0; m < 4; ++m) {
      const int row = wr * 64 + m * 16 + l16;
      const int sw = (row & 7) * 8;
      short8 a0 = *(const short8*)&As_[row * 64 + ((l4 * 8) ^ sw)];
      short8 a1 = *(const short8*)&As_[row * 64 + ((l4 * 8 + 32) ^ sw)];
#pragma unroll
      for (int n = 0; n < 4; ++n) {
        acc[m][n] = MFMA16(a0, bfr[n][0], acc[m][n]);
        acc[m][n] = MFMA16(a1, bfr[n][1], acc[m][n]);
      }
    }
    __builtin_amdgcn_s_setprio(0);
    asm volatile("" ::: "memory");
    __builtin_amdgcn_s_barrier();
    cur ^= 1;
  }

  const int row0 = bm * 128 + wr * 64, col0 = bn * 128 + wc * 64;
#pragma unroll
  for (int m = 0; m < 4; ++m) {
#pragma unroll
    for (int n = 0; n < 4; ++n) {
      const int col = col0 + n * 16 + l16;
#pragma unroll
      for (int i = 0; i < 4; ++i) {
        const int row = row0 + m * 16 + l4 * 4 + i;
        const size_t idx = (size_t)row * D_MODEL + col;
        if (RMODE == 0) {
          const float rv = ((const float*)resid)[idx];
          ((ushort*)out0)[idx] = f2bf(acc[m][n][i] + bias0[col] + rv);
        } else {
          const float rv = bf2f(((const ushort*)resid)[idx]);
          ((float*)out0)[idx] = acc[m][n][i] + bias0[col] + rv;
        }
      }
    }
  }
}

// ---------------- causal flash attention v8: paired KV tiles, 4-deep ring ------------
__global__ __launch_bounds__(256) void attn8_kernel(
    const ushort* __restrict__ Q, const ushort* __restrict__ Km,
    const ushort* __restrict__ Vt, ushort* __restrict__ O) {
  const int b = blockIdx.x;
  const int bh = (b & 7) * 8 + ((b >> 3) & 7);
  const int p = b >> 6;                      // 0..7
  const int bb = bh >> 4, hh = bh & 15;
  const int t = threadIdx.x, lane = t & 63, w = t >> 6;
  const int l16 = lane & 15, l4 = lane >> 4;
  const size_t base  = (size_t)bb * SEQ * D_MODEL + (size_t)hh * 64;
  const size_t vbase = (size_t)bh * 64 * SEQ;

  __shared__ __align__(16) ushort Ks[4][64 * 64];
  __shared__ __align__(16) ushort Vs[4][64 * 64];
  __shared__ __align__(16) ushort Pw[4][32 * 64];
  ushort* myP = &Pw[w][0];

#define STAGE(ktile, buf) do {                                                     \
    const int kv0_ = (ktile) * 64;                                                 \
    _Pragma("unroll")                                                              \
    for (int i_ = 0; i_ < 2; ++i_) {                                               \
      const int g_ = i_ * 256 + t;                                                 \
      const int row_ = g_ >> 3;                                                    \
      const int c8_ = ((g_ & 7) ^ (row_ & 7)) * 8;                                 \
      gl_lds16(&Km[base + (size_t)(kv0_ + row_) * D_MODEL + c8_],                  \
               (ushort*)&Ks[buf][(i_ * 256 + w * 64) * 8]);                        \
      gl_lds16(&Vt[vbase + (size_t)row_ * SEQ + kv0_ + c8_],                       \
               (ushort*)&Vs[buf][(i_ * 256 + w * 64) * 8]);                        \
    }                                                                              \
  } while (0)

#pragma unroll
  for (int pan = 0; pan < 2; ++pan) {
    const int qt = pan ? p : (15 - p);
    const int qb = qt * 128 + w * 32;
    const int nt = qt * 2 + 2;

    short8 qf[2][2];
#pragma unroll
    for (int qj = 0; qj < 2; ++qj)
#pragma unroll
      for (int dk = 0; dk < 2; ++dk)
        qf[qj][dk] = *(const short8*)&Q[base + (size_t)(qb + qj * 16 + l16) * D_MODEL + dk * 32 + l4 * 8];

    f32x4 oacc[4][2] = {};
    float l_i[2] = {0.0f, 0.0f};

    STAGE(0, 0);
    STAGE(1, 1);

    for (int jt = 0; jt < nt; jt += 2) {
      if (jt + 2 < nt) {
        STAGE(jt + 2, (jt + 2) & 3);
        STAGE(jt + 3, (jt + 3) & 3);
        asm volatile("s_waitcnt vmcnt(8)" ::: "memory");
      } else {
        asm volatile("s_waitcnt vmcnt(0)" ::: "memory");
      }
      __builtin_amdgcn_s_barrier();

#pragma unroll
      for (int half = 0; half < 2; ++half) {
        const int kt = jt + half;
        const int kv0 = kt * 64;
        const bool active = (kv0 <= qb + 31);
        if (active) {
          const ushort* Kc = Ks[kt & 3];
          const ushort* Vc = Vs[kt & 3];

          f32x4 sacc[2][4] = {};
          __builtin_amdgcn_s_setprio(1);
#pragma unroll
          for (int n = 0; n < 4; ++n) {
            const int r = n * 16 + l16;
            const int rs = r * 8, rx = r & 7;
#pragma unroll
            for (int dk = 0; dk < 2; ++dk) {
              short8 ak = *(const short8*)&Kc[(rs + ((dk * 4 + l4) ^ rx)) * 8];
              sacc[0][n] = MFMA16(ak, qf[0][dk], sacc[0][n]);
              sacc[1][n] = MFMA16(ak, qf[1][dk], sacc[1][n]);
            }
          }
          __builtin_amdgcn_s_setprio(0);

          const bool diag = (kv0 + 63 > qb);
#pragma unroll
          for (int qj = 0; qj < 2; ++qj) {
            const int qq = qb + qj * 16 + l16;
            const int ql = qj * 16 + l16;
            const int psw = (ql & 7) * 8;
            if (diag) {
#pragma unroll
              for (int n = 0; n < 4; ++n)
#pragma unroll
                for (int i = 0; i < 4; ++i) {
                  const int kv = kv0 + n * 16 + l4 * 4 + i;
                  if (kv > qq) sacc[qj][n][i] = -1e30f;
                }
            }
            float lsum = 0.0f;
#pragma unroll
            for (int n = 0; n < 4; ++n) {
              const float p0 = EXP2(sacc[qj][n][0]);
              const float p1 = EXP2(sacc[qj][n][1]);
              const float p2 = EXP2(sacc[qj][n][2]);
              const float p3 = EXP2(sacc[qj][n][3]);
              lsum += p0 + p1 + p2 + p3;
              ushort4 pk;
              pk.x = f2bf(p0); pk.y = f2bf(p1); pk.z = f2bf(p2); pk.w = f2bf(p3);
              *(ushort4*)&myP[ql * 64 + ((n * 16 + l4 * 4) ^ psw)] = pk;
            }
            l_i[qj] += lsum;
          }

          __builtin_amdgcn_s_setprio(1);
#pragma unroll
          for (int kk = 0; kk < 2; ++kk) {
            short8 bp[2];
#pragma unroll
            for (int qj = 0; qj < 2; ++qj) {
              const int ql = qj * 16 + l16;
              bp[qj] = *(const short8*)&myP[ql * 64 + ((kk * 32 + l4 * 8) ^ ((ql & 7) * 8))];
            }
#pragma unroll
            for (int nd = 0; nd < 4; ++nd) {
              const int r = nd * 16 + l16;
              short8 av = *(const short8*)&Vc[(r * 8 + ((kk * 4 + l4) ^ (r & 7))) * 8];
              oacc[nd][0] = MFMA16(av, bp[0], oacc[nd][0]);
              oacc[nd][1] = MFMA16(av, bp[1], oacc[nd][1]);
            }
          }
          __builtin_amdgcn_s_setprio(0);
        }
      }

      asm volatile("" ::: "memory");
      __builtin_amdgcn_s_barrier();
    }

#pragma unroll
    for (int qj = 0; qj < 2; ++qj) {
      l_i[qj] += __shfl_xor(l_i[qj], 16, 64);
      l_i[qj] += __shfl_xor(l_i[qj], 32, 64);
      const int qq = qb + qj * 16 + l16;
      const float inv = 1.0f / l_i[qj];
#pragma unroll
      for (int nd = 0; nd < 4; ++nd) {
        ushort4 r;
        r.x = f2bf(oacc[nd][qj][0] * inv);
        r.y = f2bf(oacc[nd][qj][1] * inv);
        r.z = f2bf(oacc[nd][qj][2] * inv);
        r.w = f2bf(oacc[nd][qj][3] * inv);
        *(ushort4*)&O[base + (size_t)qq * D_MODEL + nd * 16 + l4 * 4] = r;
      }
    }
  }
#undef STAGE
}

// ---------------- host launch ----------------
extern "C" void kernel_launch(void* const* d_in, const int* in_sizes, int n_in,
                              void* d_out, int out_size, void* d_ws, size_t ws_size,
                              hipStream_t stream) {
  const float* x    = (const float*)d_in[0];
  const float* ln1g = (const float*)d_in[1];
  const float* ln1b = (const float*)d_in[2];
  const float* wq   = (const float*)d_in[3];
  const float* bq   = (const float*)d_in[4];
  const float* wk   = (const float*)d_in[5];
  const float* bk   = (const float*)d_in[6];
  const float* wv   = (const float*)d_in[7];
  const float* bv   = (const float*)d_in[8];
  const float* wp   = (const float*)d_in[9];
  const float* bp   = (const float*)d_in[10];
  const float* ln2g = (const float*)d_in[11];
  const float* ln2b = (const float*)d_in[12];
  const float* w1   = (const float*)d_in[13];
  const float* b1   = (const float*)d_in[14];
  const float* w2   = (const float*)d_in[15];
  const float* b2   = (const float*)d_in[16];
  float* out = (float*)d_out;

  char* base = (char*)d_ws;
  size_t off = 0;
  auto alloc = [&](size_t bytes) -> void* {
    void* r = base + off;
    off += (bytes + 255) & ~(size_t)255;
    return r;
  };
  ushort* WqkvT = (ushort*)alloc((size_t)3 * D_MODEL * D_MODEL * 2);
  ushort* WpT   = (ushort*)alloc((size_t)D_MODEL * D_MODEL * 2);
  ushort* W1T   = (ushort*)alloc((size_t)D_FF * D_MODEL * 2);
  ushort* W2T   = (ushort*)alloc((size_t)D_MODEL * D_FF * 2);
  ushort* xn    = (ushort*)alloc((size_t)NROWS * D_MODEL * 2);
  ushort* q     = (ushort*)alloc((size_t)NROWS * D_MODEL * 2);
  ushort* k     = (ushort*)alloc((size_t)NROWS * D_MODEL * 2);
  ushort* vt    = (ushort*)alloc((size_t)NROWS * D_MODEL * 2);  // [bh][d][s]
  ushort* o     = (ushort*)alloc((size_t)NROWS * D_MODEL * 2);
  ushort* x2    = (ushort*)alloc((size_t)NROWS * D_MODEL * 2);  // bf16 residual stream
  ushort* xn2   = (ushort*)alloc((size_t)NROWS * D_MODEL * 2);
  ushort* hbuf  = (ushort*)alloc((size_t)NROWS * D_FF * 2);

  // fused weight packing + LN1: 12288 pack blocks + 8192 LN rows
  PackArgs pa;
  pa.in[0] = wq; pa.out[0] = WqkvT + (size_t)0 * D_MODEL * D_MODEL;
  pa.in[1] = wk; pa.out[1] = WqkvT + (size_t)1 * D_MODEL * D_MODEL;
  pa.in[2] = wv; pa.out[2] = WqkvT + (size_t)2 * D_MODEL * D_MODEL;
  pa.in[3] = wp; pa.out[3] = WpT;
  pa.in[4] = w1; pa.out[4] = W1T;
  pa.in[5] = w2; pa.out[5] = W2T;
  for (int j = 0; j < 3; ++j) {
    pa.K[j] = D_MODEL; pa.N[j] = D_HEAD; pa.nx[j] = 2; pa.per_batch[j] = 64;
    pa.in_bs[j] = (long)D_MODEL * D_HEAD; pa.out_bs[j] = (long)D_HEAD * D_MODEL;
  }
  pa.K[3] = D_MODEL; pa.N[3] = D_MODEL; pa.nx[3] = 32; pa.per_batch[3] = 1024;
  pa.in_bs[3] = 0; pa.out_bs[3] = 0;
  pa.K[4] = D_MODEL; pa.N[4] = D_FF; pa.nx[4] = 128; pa.per_batch[4] = 4096;
  pa.in_bs[4] = 0; pa.out_bs[4] = 0;
  pa.K[5] = D_FF; pa.N[5] = D_MODEL; pa.nx[5] = 32; pa.per_batch[5] = 4096;
  pa.in_bs[5] = 0; pa.out_bs[5] = 0;
  pa.cum[0] = 0; pa.cum[1] = 1024; pa.cum[2] = 2048; pa.cum[3] = 3072;
  pa.cum[4] = 4096; pa.cum[5] = 8192; pa.cum[6] = 12288;
  pa.lnx = x; pa.lng = ln1g; pa.lnb = ln1b; pa.lnout = xn;
  pack_ln<<<12288 + NROWS, dim3(32, 8), 0, stream>>>(pa);

  gemm256<0><<<dim3((NROWS / 256) * (3 * D_MODEL / 256)), 512, 0, stream>>>(
      xn, WqkvT, NROWS, 3 * D_MODEL, D_MODEL, bq, bk, bv, q, k, vt);
  attn8_kernel<<<512, 256, 0, stream>>>(q, k, vt, o);
  // proj: resid = x (f32), out = x2 (bf16)
  gemm128d<0><<<dim3((NROWS / 128) * (D_MODEL / 128)), 256, 0, stream>>>(
      o, WpT, NROWS, D_MODEL, D_MODEL, bp, x, x2);
  ln_bf16_kernel<<<NROWS, 256, 0, stream>>>(x2, ln2g, ln2b, xn2);
  gemm256<2><<<dim3((NROWS / 256) * (D_FF / 256)), 512, 0, stream>>>(
      xn2, W1T, NROWS, D_FF, D_MODEL, b1, nullptr, nullptr, hbuf, nullptr, nullptr);
  // FF2: resid = x2 (bf16), out = d_out (f32)
  gemm128d<1><<<dim3((NROWS / 128) * (D_MODEL / 128)), 256, 0, stream>>>(
      hbuf, W2T, NROWS, D_MODEL, D_FF, b2, x2, out);
}

// Round 20
// 344.760 us; speedup vs baseline: 1.0189x; 1.0026x over previous
//
#include <hip/hip_runtime.h>
#include <hip/hip_bf16.h>

// ---------------- problem constants ----------------
#define D_MODEL 1024
#define N_HEADS 16
#define D_HEAD  64
#define D_FF    4096
#define SEQ     2048
#define BATCH   4
#define NROWS   (BATCH * SEQ)   // 8192

typedef __attribute__((ext_vector_type(8))) short short8;    // 8 x bf16 (4 VGPR)
typedef __attribute__((ext_vector_type(4))) float f32x4;     // 16x16 mfma acc

#define EXP2(x) exp2f(x)
#define MFMA16(a, b, c) __builtin_amdgcn_mfma_f32_16x16x32_bf16(a, b, c, 0, 0, 0)

static __device__ __forceinline__ ushort f2bf(float x) {
  __hip_bfloat16 h = __float2bfloat16(x);
  return *reinterpret_cast<ushort*>(&h);
}
static __device__ __forceinline__ float bf2f(ushort u) {
  unsigned int v = ((unsigned int)u) << 16;
  return *reinterpret_cast<float*>(&v);
}

// async global->LDS, 16B per lane. LDS dest is wave-uniform base (+lane*16 by HW).
static __device__ __forceinline__ void gl_lds16(const ushort* g, ushort* l) {
  __builtin_amdgcn_global_load_lds(
      (const __attribute__((address_space(1))) void*)g,
      (__attribute__((address_space(3))) void*)l, 16, 0, 0);
}

// ---------------- fused weight packing + LN1: 6 transpose jobs + 8192 LN rows -------
struct PackArgs {
  const float* in[6];
  ushort* out[6];
  int K[6], N[6], nx[6], per_batch[6];
  long in_bs[6], out_bs[6];
  int cum[7];
  const float* lnx; const float* lng; const float* lnb; ushort* lnout;
};

__global__ __launch_bounds__(256) void pack_ln(PackArgs a) {
  const int b = blockIdx.x;
  __shared__ float tile[32][33];

  if (b >= a.cum[6]) {
    // ---- LN1 row ----
    const int row = b - a.cum[6];
    const int t = threadIdx.y * 32 + threadIdx.x;
    const float4 v = *(const float4*)(a.lnx + (size_t)row * D_MODEL + t * 4);
    float s  = v.x + v.y + v.z + v.w;
    float ss = v.x * v.x + v.y * v.y + v.z * v.z + v.w * v.w;
#pragma unroll
    for (int off = 1; off < 64; off <<= 1) {
      s  += __shfl_xor(s, off, 64);
      ss += __shfl_xor(ss, off, 64);
    }
    float* red = &tile[0][0];
    const int w = t >> 6;
    if ((t & 63) == 0) { red[w] = s; red[4 + w] = ss; }
    __syncthreads();
    s  = red[0] + red[1] + red[2] + red[3];
    ss = red[4] + red[5] + red[6] + red[7];
    const float mu  = s * (1.0f / D_MODEL);
    const float var = ss * (1.0f / D_MODEL) - mu * mu;
    const float rstd = rsqrtf(var + 1e-5f);
    const float4 gg = *(const float4*)(a.lng + t * 4);
    const float4 bb = *(const float4*)(a.lnb + t * 4);
    ushort4 r;
    r.x = f2bf((v.x - mu) * rstd * gg.x + bb.x);
    r.y = f2bf((v.y - mu) * rstd * gg.y + bb.y);
    r.z = f2bf((v.z - mu) * rstd * gg.z + bb.z);
    r.w = f2bf((v.w - mu) * rstd * gg.w + bb.w);
    *(ushort4*)(a.lnout + (size_t)row * D_MODEL + t * 4) = r;
    return;
  }

  // ---- pack job ----
  int j = 0;
#pragma unroll
  for (int i = 0; i < 5; ++i) if (b >= a.cum[i + 1]) j = i + 1;
  const int tidx = b - a.cum[j];
  const int bz = tidx / a.per_batch[j];
  const int rem = tidx % a.per_batch[j];
  const int n0 = (rem % a.nx[j]) * 32;
  const int k0 = (rem / a.nx[j]) * 32;
  const float* in = a.in[j] + (long)bz * a.in_bs[j];
  ushort* out = a.out[j] + (long)bz * a.out_bs[j];
  const int K = a.K[j], N = a.N[j];

  const int tx = threadIdx.x, ty = threadIdx.y;
#pragma unroll
  for (int i = 0; i < 32; i += 8)
    tile[ty + i][tx] = in[(size_t)(k0 + ty + i) * N + n0 + tx];
  __syncthreads();
#pragma unroll
  for (int i = 0; i < 32; i += 8)
    out[(size_t)(n0 + ty + i) * K + k0 + tx] = f2bf(tile[tx][ty + i]);
}

// ---------------- LayerNorm (bf16 in, bf16 out) ----------------
__global__ __launch_bounds__(256) void ln_bf16_kernel(
    const ushort* __restrict__ x, const float* __restrict__ g,
    const float* __restrict__ b, ushort* __restrict__ out) {
  int row = blockIdx.x, t = threadIdx.x;
  const ushort4 u = *(const ushort4*)(x + (size_t)row * D_MODEL + t * 4);
  float4 v;
  v.x = bf2f(u.x); v.y = bf2f(u.y); v.z = bf2f(u.z); v.w = bf2f(u.w);
  float s  = v.x + v.y + v.z + v.w;
  float ss = v.x * v.x + v.y * v.y + v.z * v.z + v.w * v.w;
#pragma unroll
  for (int off = 1; off < 64; off <<= 1) {
    s  += __shfl_xor(s, off, 64);
    ss += __shfl_xor(ss, off, 64);
  }
  __shared__ float rs_[4], rss_[4];
  int w = t >> 6;
  if ((t & 63) == 0) { rs_[w] = s; rss_[w] = ss; }
  __syncthreads();
  s  = rs_[0] + rs_[1] + rs_[2] + rs_[3];
  ss = rss_[0] + rss_[1] + rss_[2] + rss_[3];
  float mu  = s * (1.0f / D_MODEL);
  float var = ss * (1.0f / D_MODEL) - mu * mu;
  float rstd = rsqrtf(var + 1e-5f);
  float4 gg = *(const float4*)(g + t * 4);
  float4 bb = *(const float4*)(b + t * 4);
  ushort4 r;
  r.x = f2bf((v.x - mu) * rstd * gg.x + bb.x);
  r.y = f2bf((v.y - mu) * rstd * gg.y + bb.y);
  r.z = f2bf((v.z - mu) * rstd * gg.z + bb.z);
  r.w = f2bf((v.w - mu) * rstd * gg.w + bb.w);
  *(ushort4*)(out + (size_t)row * D_MODEL + t * 4) = r;
}

// ---------------- 256x256 bf16 MFMA GEMM, counted-vmcnt double-buffer ---------------
// MODE 0: QKV (out0=q bf16 scaled, out1=k bf16, out2 = V TRANSPOSED [bh][d][s])
// MODE 2: FF1 relu -> bf16   (NO setprio: 8-wave lockstep = m190 null/neg regime)
template <int MODE>
__global__ __launch_bounds__(512, 2) void gemm256(
    const ushort* __restrict__ A, const ushort* __restrict__ BT,
    int M, int N, int K,
    const float* __restrict__ bias0, const float* __restrict__ bias1,
    const float* __restrict__ bias2,
    void* __restrict__ out0, void* __restrict__ out1, void* __restrict__ out2) {
  __shared__ __align__(16) ushort As[2][256 * 64];
  __shared__ __align__(16) ushort Bs[2][256 * 64];
  const int gx = N >> 8;
  const int nwg = gx * (M >> 8);
  const int cpx = nwg >> 3;
  const int tile = (blockIdx.x & 7) * cpx + (blockIdx.x >> 3);
  const int bn = tile % gx, bm = tile / gx;
  const int t = threadIdx.x, lane = t & 63, w = t >> 6;
  const int wr = w >> 2, wc = w & 3;
  const int l16 = lane & 15, l4 = lane >> 4;

  const ushort* Ab = A + (size_t)(bm * 256) * K;
  const ushort* Bb = BT + (size_t)(bn * 256) * K;

  int srow[4], scol[4];
#pragma unroll
  for (int i = 0; i < 4; ++i) {
    int c = i * 512 + t;
    srow[i] = c >> 3;
    scol[i] = 8 * ((c & 7) ^ ((c >> 3) & 7));
  }

  f32x4 acc[8][4] = {};
  int cur = 0;
  const int nk = K >> 6;

#pragma unroll
  for (int i = 0; i < 4; ++i) {
    gl_lds16(&Ab[(size_t)srow[i] * K + scol[i]], (ushort*)&As[0][(i * 512 + w * 64) * 8]);
    gl_lds16(&Bb[(size_t)srow[i] * K + scol[i]], (ushort*)&Bs[0][(i * 512 + w * 64) * 8]);
  }

  for (int kt = 0; kt < nk; ++kt) {
    if (kt + 1 < nk) {
      const int k0n = (kt + 1) << 6;
#pragma unroll
      for (int i = 0; i < 4; ++i) {
        gl_lds16(&Ab[(size_t)srow[i] * K + k0n + scol[i]], (ushort*)&As[cur ^ 1][(i * 512 + w * 64) * 8]);
        gl_lds16(&Bb[(size_t)srow[i] * K + k0n + scol[i]], (ushort*)&Bs[cur ^ 1][(i * 512 + w * 64) * 8]);
      }
      asm volatile("s_waitcnt vmcnt(8)" ::: "memory");  // prev tile landed; 8 in flight
    } else {
      asm volatile("s_waitcnt vmcnt(0)" ::: "memory");
    }
    __builtin_amdgcn_s_barrier();

    const ushort* As_ = As[cur];
    const ushort* Bs_ = Bs[cur];
    short8 bfr[4][2];
#pragma unroll
    for (int n = 0; n < 4; ++n) {
      const int row = wc * 64 + n * 16 + l16;
      const int sw = (row & 7) * 8;
      bfr[n][0] = *(const short8*)&Bs_[row * 64 + ((l4 * 8) ^ sw)];
      bfr[n][1] = *(const short8*)&Bs_[row * 64 + ((l4 * 8 + 32) ^ sw)];
    }
#pragma unroll
    for (int m = 0; m < 8; ++m) {
      const int row = wr * 128 + m * 16 + l16;
      const int sw = (row & 7) * 8;
      short8 a0 = *(const short8*)&As_[row * 64 + ((l4 * 8) ^ sw)];
      short8 a1 = *(const short8*)&As_[row * 64 + ((l4 * 8 + 32) ^ sw)];
#pragma unroll
      for (int n = 0; n < 4; ++n) {
        acc[m][n] = MFMA16(a0, bfr[n][0], acc[m][n]);
        acc[m][n] = MFMA16(a1, bfr[n][1], acc[m][n]);
      }
    }
    asm volatile("" ::: "memory");
    __builtin_amdgcn_s_barrier();   // ds_reads done before anyone overwrites cur
    cur ^= 1;
  }

  const int row0 = bm * 256 + wr * 128, col0 = bn * 256 + wc * 64;
#pragma unroll
  for (int m = 0; m < 8; ++m) {
#pragma unroll
    for (int n = 0; n < 4; ++n) {
      const int col = col0 + n * 16 + l16;
      if (MODE == 0) {
        const int which = col >> 10;          // uniform per fragment
        const int c = col & 1023;
        if (which < 2) {
          const float* bp_ = (which == 0) ? bias0 : bias1;
          ushort* op = (which == 0) ? (ushort*)out0 : (ushort*)out1;
          const float scale = (which == 0) ? 0.125f * 1.44269504f : 1.0f;
#pragma unroll
          for (int i = 0; i < 4; ++i) {
            const int row = row0 + m * 16 + l4 * 4 + i;
            op[(size_t)row * D_MODEL + c] = f2bf((acc[m][n][i] + bp_[c]) * scale);
          }
        } else {
          // v: write transposed into vt[bh][d][s]; 4 consecutive s per lane -> 8B store
          const int d = c & 63, hh2 = c >> 6;
          const float bv_ = bias2[c];
          ushort4 r4;
          r4.x = f2bf(acc[m][n][0] + bv_);
          r4.y = f2bf(acc[m][n][1] + bv_);
          r4.z = f2bf(acc[m][n][2] + bv_);
          r4.w = f2bf(acc[m][n][3] + bv_);
          const int row = row0 + m * 16 + l4 * 4;
          const int bb2 = row >> 11, s = row & 2047;
          *(ushort4*)((ushort*)out2 + ((size_t)(bb2 * 16 + hh2) * 64 + d) * SEQ + s) = r4;
        }
      } else {
#pragma unroll
        for (int i = 0; i < 4; ++i) {
          const int row = row0 + m * 16 + l4 * 4 + i;
          const float val = fmaxf(acc[m][n][i] + bias0[col], 0.0f);
          ((ushort*)out0)[(size_t)row * D_FF + col] = f2bf(val);
        }
      }
    }
  }
}

// ---------------- 128x128 dbuf counted-vmcnt GEMM (16x16 MFMA), 2 blocks/CU ---------
// RMODE 0 (proj): resid f32, out bf16 = C + bias + resid
// RMODE 1 (FF2):  resid bf16, out f32 = C + bias + resid
template <int RMODE>
__global__ __launch_bounds__(256, 2) void gemm128d(
    const ushort* __restrict__ A, const ushort* __restrict__ BT,
    int M, int N, int K,
    const float* __restrict__ bias0, const void* __restrict__ resid,
    void* __restrict__ out0) {
  __shared__ __align__(16) ushort As[2][128 * 64];
  __shared__ __align__(16) ushort Bs[2][128 * 64];
  const int gx = N >> 7;
  const int nwg = gx * (M >> 7);
  const int cpx = nwg >> 3;
  const int tile = (blockIdx.x & 7) * cpx + (blockIdx.x >> 3);
  const int bn = tile % gx, bm = tile / gx;
  const int t = threadIdx.x, lane = t & 63, w = t >> 6;
  const int wr = w >> 1, wc = w & 1;
  const int l16 = lane & 15, l4 = lane >> 4;

  const ushort* Ab = A + (size_t)(bm * 128) * K;
  const ushort* Bb = BT + (size_t)(bn * 128) * K;

  int srow[4], scol[4];
#pragma unroll
  for (int i = 0; i < 4; ++i) {
    int c = i * 256 + t;
    srow[i] = c >> 3;
    scol[i] = 8 * ((c & 7) ^ ((c >> 3) & 7));
  }

  f32x4 acc[4][4] = {};
  int cur = 0;
  const int nk = K >> 6;

#pragma unroll
  for (int i = 0; i < 4; ++i) {
    gl_lds16(&Ab[(size_t)srow[i] * K + scol[i]], (ushort*)&As[0][(i * 256 + w * 64) * 8]);
    gl_lds16(&Bb[(size_t)srow[i] * K + scol[i]], (ushort*)&Bs[0][(i * 256 + w * 64) * 8]);
  }

  for (int kt = 0; kt < nk; ++kt) {
    if (kt + 1 < nk) {
      const int k0n = (kt + 1) << 6;
#pragma unroll
      for (int i = 0; i < 4; ++i) {
        gl_lds16(&Ab[(size_t)srow[i] * K + k0n + scol[i]], (ushort*)&As[cur ^ 1][(i * 256 + w * 64) * 8]);
        gl_lds16(&Bb[(size_t)srow[i] * K + k0n + scol[i]], (ushort*)&Bs[cur ^ 1][(i * 256 + w * 64) * 8]);
      }
      asm volatile("s_waitcnt vmcnt(8)" ::: "memory");
    } else {
      asm volatile("s_waitcnt vmcnt(0)" ::: "memory");
    }
    __builtin_amdgcn_s_barrier();

    const ushort* As_ = As[cur];
    const ushort* Bs_ = Bs[cur];
    short8 bfr[4][2];
#pragma unroll
    for (int n = 0; n < 4; ++n) {
      const int row = wc * 64 + n * 16 + l16;
      const int sw = (row & 7) * 8;
      bfr[n][0] = *(const short8*)&Bs_[row * 64 + ((l4 * 8) ^ sw)];
      bfr[n][1] = *(const short8*)&Bs_[row * 64 + ((l4 * 8 + 32) ^ sw)];
    }
    __builtin_amdgcn_s_setprio(1);
#pragma unroll
    for (int m = 0; m < 4; ++m) {
      const int row = wr * 64 + m * 16 + l16;
      const int sw = (row & 7) * 8;
      short8 a0 = *(const short8*)&As_[row * 64 + ((l4 * 8) ^ sw)];
      short8 a1 = *(const short8*)&As_[row * 64 + ((l4 * 8 + 32) ^ sw)];
#pragma unroll
      for (int n = 0; n < 4; ++n) {
        acc[m][n] = MFMA16(a0, bfr[n][0], acc[m][n]);
        acc[m][n] = MFMA16(a1, bfr[n][1], acc[m][n]);
      }
    }
    __builtin_amdgcn_s_setprio(0);
    asm volatile("" ::: "memory");
    __builtin_amdgcn_s_barrier();
    cur ^= 1;
  }

  const int row0 = bm * 128 + wr * 64, col0 = bn * 128 + wc * 64;
#pragma unroll
  for (int m = 0; m < 4; ++m) {
#pragma unroll
    for (int n = 0; n < 4; ++n) {
      const int col = col0 + n * 16 + l16;
#pragma unroll
      for (int i = 0; i < 4; ++i) {
        const int row = row0 + m * 16 + l4 * 4 + i;
        const size_t idx = (size_t)row * D_MODEL + col;
        if (RMODE == 0) {
          const float rv = ((const float*)resid)[idx];
          ((ushort*)out0)[idx] = f2bf(acc[m][n][i] + bias0[col] + rv);
        } else {
          const float rv = bf2f(((const ushort*)resid)[idx]);
          ((float*)out0)[idx] = acc[m][n][i] + bias0[col] + rv;
        }
      }
    }
  }
}

// ---------------- causal flash attention v8: paired KV tiles, 4-deep ring ------------
// (no setprio: R17 vs R19 A/B showed consistent ~+0.7us cost with it)
__global__ __launch_bounds__(256) void attn8_kernel(
    const ushort* __restrict__ Q, const ushort* __restrict__ Km,
    const ushort* __restrict__ Vt, ushort* __restrict__ O) {
  const int b = blockIdx.x;
  const int bh = (b & 7) * 8 + ((b >> 3) & 7);
  const int p = b >> 6;                      // 0..7
  const int bb = bh >> 4, hh = bh & 15;
  const int t = threadIdx.x, lane = t & 63, w = t >> 6;
  const int l16 = lane & 15, l4 = lane >> 4;
  const size_t base  = (size_t)bb * SEQ * D_MODEL + (size_t)hh * 64;
  const size_t vbase = (size_t)bh * 64 * SEQ;

  __shared__ __align__(16) ushort Ks[4][64 * 64];
  __shared__ __align__(16) ushort Vs[4][64 * 64];
  __shared__ __align__(16) ushort Pw[4][32 * 64];
  ushort* myP = &Pw[w][0];

#define STAGE(ktile, buf) do {                                                     \
    const int kv0_ = (ktile) * 64;                                                 \
    _Pragma("unroll")                                                              \
    for (int i_ = 0; i_ < 2; ++i_) {                                               \
      const int g_ = i_ * 256 + t;                                                 \
      const int row_ = g_ >> 3;                                                    \
      const int c8_ = ((g_ & 7) ^ (row_ & 7)) * 8;                                 \
      gl_lds16(&Km[base + (size_t)(kv0_ + row_) * D_MODEL + c8_],                  \
               (ushort*)&Ks[buf][(i_ * 256 + w * 64) * 8]);                        \
      gl_lds16(&Vt[vbase + (size_t)row_ * SEQ + kv0_ + c8_],                       \
               (ushort*)&Vs[buf][(i_ * 256 + w * 64) * 8]);                        \
    }                                                                              \
  } while (0)

#pragma unroll
  for (int pan = 0; pan < 2; ++pan) {
    const int qt = pan ? p : (15 - p);
    const int qb = qt * 128 + w * 32;
    const int nt = qt * 2 + 2;

    short8 qf[2][2];
#pragma unroll
    for (int qj = 0; qj < 2; ++qj)
#pragma unroll
      for (int dk = 0; dk < 2; ++dk)
        qf[qj][dk] = *(const short8*)&Q[base + (size_t)(qb + qj * 16 + l16) * D_MODEL + dk * 32 + l4 * 8];

    f32x4 oacc[4][2] = {};
    float l_i[2] = {0.0f, 0.0f};

    STAGE(0, 0);
    STAGE(1, 1);

    for (int jt = 0; jt < nt; jt += 2) {
      if (jt + 2 < nt) {
        STAGE(jt + 2, (jt + 2) & 3);
        STAGE(jt + 3, (jt + 3) & 3);
        asm volatile("s_waitcnt vmcnt(8)" ::: "memory");
      } else {
        asm volatile("s_waitcnt vmcnt(0)" ::: "memory");
      }
      __builtin_amdgcn_s_barrier();

#pragma unroll
      for (int half = 0; half < 2; ++half) {
        const int kt = jt + half;
        const int kv0 = kt * 64;
        const bool active = (kv0 <= qb + 31);
        if (active) {
          const ushort* Kc = Ks[kt & 3];
          const ushort* Vc = Vs[kt & 3];

          f32x4 sacc[2][4] = {};
#pragma unroll
          for (int n = 0; n < 4; ++n) {
            const int r = n * 16 + l16;
            const int rs = r * 8, rx = r & 7;
#pragma unroll
            for (int dk = 0; dk < 2; ++dk) {
              short8 ak = *(const short8*)&Kc[(rs + ((dk * 4 + l4) ^ rx)) * 8];
              sacc[0][n] = MFMA16(ak, qf[0][dk], sacc[0][n]);
              sacc[1][n] = MFMA16(ak, qf[1][dk], sacc[1][n]);
            }
          }

          const bool diag = (kv0 + 63 > qb);
#pragma unroll
          for (int qj = 0; qj < 2; ++qj) {
            const int qq = qb + qj * 16 + l16;
            const int ql = qj * 16 + l16;
            const int psw = (ql & 7) * 8;
            if (diag) {
#pragma unroll
              for (int n = 0; n < 4; ++n)
#pragma unroll
                for (int i = 0; i < 4; ++i) {
                  const int kv = kv0 + n * 16 + l4 * 4 + i;
                  if (kv > qq) sacc[qj][n][i] = -1e30f;
                }
            }
            float lsum = 0.0f;
#pragma unroll
            for (int n = 0; n < 4; ++n) {
              const float p0 = EXP2(sacc[qj][n][0]);
              const float p1 = EXP2(sacc[qj][n][1]);
              const float p2 = EXP2(sacc[qj][n][2]);
              const float p3 = EXP2(sacc[qj][n][3]);
              lsum += p0 + p1 + p2 + p3;
              ushort4 pk;
              pk.x = f2bf(p0); pk.y = f2bf(p1); pk.z = f2bf(p2); pk.w = f2bf(p3);
              *(ushort4*)&myP[ql * 64 + ((n * 16 + l4 * 4) ^ psw)] = pk;
            }
            l_i[qj] += lsum;
          }

#pragma unroll
          for (int kk = 0; kk < 2; ++kk) {
            short8 bp[2];
#pragma unroll
            for (int qj = 0; qj < 2; ++qj) {
              const int ql = qj * 16 + l16;
              bp[qj] = *(const short8*)&myP[ql * 64 + ((kk * 32 + l4 * 8) ^ ((ql & 7) * 8))];
            }
#pragma unroll
            for (int nd = 0; nd < 4; ++nd) {
              const int r = nd * 16 + l16;
              short8 av = *(const short8*)&Vc[(r * 8 + ((kk * 4 + l4) ^ (r & 7))) * 8];
              oacc[nd][0] = MFMA16(av, bp[0], oacc[nd][0]);
              oacc[nd][1] = MFMA16(av, bp[1], oacc[nd][1]);
            }
          }
        }
      }

      asm volatile("" ::: "memory");
      __builtin_amdgcn_s_barrier();
    }

#pragma unroll
    for (int qj = 0; qj < 2; ++qj) {
      l_i[qj] += __shfl_xor(l_i[qj], 16, 64);
      l_i[qj] += __shfl_xor(l_i[qj], 32, 64);
      const int qq = qb + qj * 16 + l16;
      const float inv = 1.0f / l_i[qj];
#pragma unroll
      for (int nd = 0; nd < 4; ++nd) {
        ushort4 r;
        r.x = f2bf(oacc[nd][qj][0] * inv);
        r.y = f2bf(oacc[nd][qj][1] * inv);
        r.z = f2bf(oacc[nd][qj][2] * inv);
        r.w = f2bf(oacc[nd][qj][3] * inv);
        *(ushort4*)&O[base + (size_t)qq * D_MODEL + nd * 16 + l4 * 4] = r;
      }
    }
  }
#undef STAGE
}

// ---------------- host launch ----------------
extern "C" void kernel_launch(void* const* d_in, const int* in_sizes, int n_in,
                              void* d_out, int out_size, void* d_ws, size_t ws_size,
                              hipStream_t stream) {
  const float* x    = (const float*)d_in[0];
  const float* ln1g = (const float*)d_in[1];
  const float* ln1b = (const float*)d_in[2];
  const float* wq   = (const float*)d_in[3];
  const float* bq   = (const float*)d_in[4];
  const float* wk   = (const float*)d_in[5];
  const float* bk   = (const float*)d_in[6];
  const float* wv   = (const float*)d_in[7];
  const float* bv   = (const float*)d_in[8];
  const float* wp   = (const float*)d_in[9];
  const float* bp   = (const float*)d_in[10];
  const float* ln2g = (const float*)d_in[11];
  const float* ln2b = (const float*)d_in[12];
  const float* w1   = (const float*)d_in[13];
  const float* b1   = (const float*)d_in[14];
  const float* w2   = (const float*)d_in[15];
  const float* b2   = (const float*)d_in[16];
  float* out = (float*)d_out;

  char* base = (char*)d_ws;
  size_t off = 0;
  auto alloc = [&](size_t bytes) -> void* {
    void* r = base + off;
    off += (bytes + 255) & ~(size_t)255;
    return r;
  };
  ushort* WqkvT = (ushort*)alloc((size_t)3 * D_MODEL * D_MODEL * 2);
  ushort* WpT   = (ushort*)alloc((size_t)D_MODEL * D_MODEL * 2);
  ushort* W1T   = (ushort*)alloc((size_t)D_FF * D_MODEL * 2);
  ushort* W2T   = (ushort*)alloc((size_t)D_MODEL * D_FF * 2);
  ushort* xn    = (ushort*)alloc((size_t)NROWS * D_MODEL * 2);
  ushort* q     = (ushort*)alloc((size_t)NROWS * D_MODEL * 2);
  ushort* k     = (ushort*)alloc((size_t)NROWS * D_MODEL * 2);
  ushort* vt    = (ushort*)alloc((size_t)NROWS * D_MODEL * 2);  // [bh][d][s]
  ushort* o     = (ushort*)alloc((size_t)NROWS * D_MODEL * 2);
  ushort* x2    = (ushort*)alloc((size_t)NROWS * D_MODEL * 2);  // bf16 residual stream
  ushort* xn2   = (ushort*)alloc((size_t)NROWS * D_MODEL * 2);
  ushort* hbuf  = (ushort*)alloc((size_t)NROWS * D_FF * 2);

  // fused weight packing + LN1: 12288 pack blocks + 8192 LN rows
  PackArgs pa;
  pa.in[0] = wq; pa.out[0] = WqkvT + (size_t)0 * D_MODEL * D_MODEL;
  pa.in[1] = wk; pa.out[1] = WqkvT + (size_t)1 * D_MODEL * D_MODEL;
  pa.in[2] = wv; pa.out[2] = WqkvT + (size_t)2 * D_MODEL * D_MODEL;
  pa.in[3] = wp; pa.out[3] = WpT;
  pa.in[4] = w1; pa.out[4] = W1T;
  pa.in[5] = w2; pa.out[5] = W2T;
  for (int j = 0; j < 3; ++j) {
    pa.K[j] = D_MODEL; pa.N[j] = D_HEAD; pa.nx[j] = 2; pa.per_batch[j] = 64;
    pa.in_bs[j] = (long)D_MODEL * D_HEAD; pa.out_bs[j] = (long)D_HEAD * D_MODEL;
  }
  pa.K[3] = D_MODEL; pa.N[3] = D_MODEL; pa.nx[3] = 32; pa.per_batch[3] = 1024;
  pa.in_bs[3] = 0; pa.out_bs[3] = 0;
  pa.K[4] = D_MODEL; pa.N[4] = D_FF; pa.nx[4] = 128; pa.per_batch[4] = 4096;
  pa.in_bs[4] = 0; pa.out_bs[4] = 0;
  pa.K[5] = D_FF; pa.N[5] = D_MODEL; pa.nx[5] = 32; pa.per_batch[5] = 4096;
  pa.in_bs[5] = 0; pa.out_bs[5] = 0;
  pa.cum[0] = 0; pa.cum[1] = 1024; pa.cum[2] = 2048; pa.cum[3] = 3072;
  pa.cum[4] = 4096; pa.cum[5] = 8192; pa.cum[6] = 12288;
  pa.lnx = x; pa.lng = ln1g; pa.lnb = ln1b; pa.lnout = xn;
  pack_ln<<<12288 + NROWS, dim3(32, 8), 0, stream>>>(pa);

  gemm256<0><<<dim3((NROWS / 256) * (3 * D_MODEL / 256)), 512, 0, stream>>>(
      xn, WqkvT, NROWS, 3 * D_MODEL, D_MODEL, bq, bk, bv, q, k, vt);
  attn8_kernel<<<512, 256, 0, stream>>>(q, k, vt, o);
  // proj: resid = x (f32), out = x2 (bf16)
  gemm128d<0><<<dim3((NROWS / 128) * (D_MODEL / 128)), 256, 0, stream>>>(
      o, WpT, NROWS, D_MODEL, D_MODEL, bp, x, x2);
  ln_bf16_kernel<<<NROWS, 256, 0, stream>>>(x2, ln2g, ln2b, xn2);
  gemm256<2><<<dim3((NROWS / 256) * (D_FF / 256)), 512, 0, stream>>>(
      xn2, W1T, NROWS, D_FF, D_MODEL, b1, nullptr, nullptr, hbuf, nullptr, nullptr);
  // FF2: resid = x2 (bf16), out = d_out (f32)
  gemm128d<1><<<dim3((NROWS / 128) * (D_MODEL / 128)), 256, 0, stream>>>(
      hbuf, W2T, NROWS, D_MODEL, D_FF, b2, x2, out);
}